// Round 10
// baseline (160.690 us; speedup 1.0000x reference)
//
#include <hip/hip_runtime.h>
#include <math.h>

#define SEQ 2048
#define NH 8
#define HD 128
#define DIMF 1024
#define LOG2E 1.4426950408889634f
#define INVTAU 0.08838834764831845f

typedef __attribute__((ext_vector_type(8))) short bf16x8;
typedef __attribute__((ext_vector_type(8))) unsigned short us8;
typedef __attribute__((ext_vector_type(4))) float f32x4;
typedef __attribute__((ext_vector_type(16))) float f32x16;

// persistent scratch (fully rewritten every launch; no stale-state dependence)
__device__ float g_itacc[NH*SEQ];
__device__ float g_ftacc[NH*SEQ];
__device__ float g_aL[NH*SEQ];     // (itilde - csum) * log2e
__device__ float g_cmL[NH*SEQ];    // cummax(a) * log2e
__device__ float g_en[NH*SEQ];     // exp(-(csum + cummax)) = exp(-max_d)
__device__ unsigned short g_Qb[NH*SEQ*HD];  // bf16, [h][s][d]
__device__ unsigned short g_Kb[NH*SEQ*HD];
__device__ unsigned short g_Vb[NH*SEQ*HD];
__device__ unsigned short g_Vt[NH*HD*SEQ];  // bf16, [h][d][s]  (V transposed)
__device__ unsigned short g_Wb[16*3072];    // bf16, rows 0..7 = Wi, 8..15 = Wf

__device__ __forceinline__ unsigned short f2bf(float x) {
  unsigned u = __float_as_uint(x);
  u += 0x7fffu + ((u >> 16) & 1u);   // RNE
  return (unsigned short)(u >> 16);
}

__device__ __forceinline__ unsigned packbf(float lo, float hi) {
  return (unsigned)f2bf(lo) | ((unsigned)f2bf(hi) << 16);
}

// ------- kernel 1: q/k/v fp32 -> bf16 [h][s][d]  +  Wi/Wf -> bf16 (merged) -------
__global__ __launch_bounds__(256) void convert_kernel(const float* __restrict__ q,
                                                      const float* __restrict__ k,
                                                      const float* __restrict__ v,
                                                      const float* __restrict__ Wi,
                                                      const float* __restrict__ Wf) {
  const int bid = blockIdx.x;
  if (bid < 6144) {
    const int s = bid & 2047;
    const int t = bid >> 11;
    const float* src = (t == 0) ? q : (t == 1) ? k : v;
    unsigned short* dst = (t == 0) ? g_Qb : (t == 1) ? g_Kb : g_Vb;
    const int c = threadIdx.x * 4;
    const float4 f = *(const float4*)(src + s*DIMF + c);
    const int h = c >> 7, d = c & 127;
    ushort4 u;
    u.x = f2bf(f.x); u.y = f2bf(f.y); u.z = f2bf(f.z); u.w = f2bf(f.w);
    *(ushort4*)(dst + (h*SEQ + s)*HD + d) = u;
  } else {
    const int gid = (bid - 6144) * 256 + threadIdx.x;
    const int e4 = gid * 4;           // 48 blocks * 1024 = 49152 = 16*3072 exactly
    const int p = e4 / 3072;
    const int c = e4 % 3072;
    const float* src = (p < 8) ? (Wi + p*3072 + c) : (Wf + (p-8)*3072 + c);
    const float4 f = *(const float4*)src;
    ushort4 u;
    u.x = f2bf(f.x); u.y = f2bf(f.y); u.z = f2bf(f.z); u.w = f2bf(f.w);
    *(ushort4*)(g_Wb + p*3072 + c) = u;
  }
}

// ------- kernel 2: V transpose  g_Vb[h][s][d] -> g_Vt[h][d][s] -------
__global__ __launch_bounds__(256) void vtrans_kernel() {
  __shared__ __align__(16) unsigned short Ts[64*72];
  const int h  = blockIdx.x;
  const int s0 = blockIdx.y * 64;
  const int d0 = blockIdx.z * 64;
  const int t = threadIdx.x;
  { // load 64 s-rows x 64 d-cols, coalesced
    const int sr = t >> 2;
    const int c  = (t & 3) * 16;
    const unsigned short* src = g_Vb + (h*SEQ + s0 + sr)*HD + d0 + c;
    *(us8*)&Ts[sr*72 + c]     = *(const us8*)&src[0];
    *(us8*)&Ts[sr*72 + c + 8] = *(const us8*)&src[8];
  }
  __syncthreads();
  { // store: wave w covers s-cols [w*16,w*16+16), lane l = output d-row
    const int w = t >> 6, l = t & 63;
    unsigned short outv[16];
    #pragma unroll
    for (int j = 0; j < 16; ++j) outv[j] = Ts[(w*16 + j)*72 + l];
    unsigned short* dst = g_Vt + (h*HD + d0 + l)*SEQ + s0 + w*16;
    *(us8*)&dst[0] = *(us8*)&outv[0];
    *(us8*)&dst[8] = *(us8*)&outv[8];
  }
}

// ------- kernel 3: gate projections via MFMA (M=2048, N=16, K=3072) -------
__global__ __launch_bounds__(256) void gates_kernel() {
  __shared__ f32x4 red[4][64];
  const int tid = threadIdx.x;
  const int wave = tid >> 6, lane = tid & 63;
  const int q4 = lane >> 4, l16 = lane & 15;
  const int s0 = blockIdx.x * 16;
  f32x4 acc = {0.f, 0.f, 0.f, 0.f};
  #pragma unroll 8
  for (int ks = wave*24; ks < wave*24 + 24; ++ks) {
    const int k0 = ks*32 + q4*8;          // global k of this lane's 8 elems
    const int tsel = k0 >> 10;
    const int rem = k0 & 1023;
    const int hh = rem >> 7, dd = rem & 127;
    const unsigned short* base = (tsel == 0) ? g_Qb : (tsel == 1) ? g_Kb : g_Vb;
    const bf16x8 a = *(const bf16x8*)&base[(hh*SEQ + s0 + l16)*HD + dd];
    const bf16x8 b = *(const bf16x8*)&g_Wb[l16*3072 + k0];
    acc = __builtin_amdgcn_mfma_f32_16x16x32_bf16(a, b, acc, 0, 0, 0);
  }
  red[wave][lane] = acc;
  __syncthreads();
  if (wave == 0) {
    f32x4 s = red[0][lane];
    #pragma unroll
    for (int w = 1; w < 4; ++w) s += red[w][lane];
    #pragma unroll
    for (int r = 0; r < 4; ++r) {
      const int sg = s0 + 4*q4 + r;       // C/D: row = quad*4+reg, col = l16
      if (l16 < 8) g_itacc[l16*SEQ + sg] = s[r];
      else         g_ftacc[(l16-8)*SEQ + sg] = s[r];
    }
  }
}

// ------- kernel 4: per-head scans (block scan, 256 threads, 8 elems/thread) -------
__global__ __launch_bounds__(256) void scan_kernel(const float* __restrict__ Wi_b,
                                                   const float* __restrict__ Wf_b) {
  __shared__ float Wsum[4];
  __shared__ float Wmax[4];
  const int h = blockIdx.x;
  const int t = threadIdx.x;
  const int wave = t >> 6, lane = t & 63;
  const float ib = Wi_b[h];
  const float fb = Wf_b[h];
  const int base = h*SEQ + t*8;

  float it[8], ft[8];
  *(float4*)&it[0] = *(const float4*)&g_itacc[base];
  *(float4*)&it[4] = *(const float4*)&g_itacc[base+4];
  *(float4*)&ft[0] = *(const float4*)&g_ftacc[base];
  *(float4*)&ft[4] = *(const float4*)&g_ftacc[base+4];

  float cs[8];
  float run = 0.f;
  #pragma unroll
  for (int j = 0; j < 8; ++j) {
    const float f = ft[j] + fb;
    const float ls = fminf(f, 0.f) - log1pf(expf(-fabsf(f)));  // logsigmoid
    run += ls;
    cs[j] = run;
  }
  float x = run;
  #pragma unroll
  for (int off = 1; off < 64; off <<= 1) {
    const float tv = __shfl_up(x, off, 64);
    if (lane >= off) x += tv;
  }
  const float wexcl = x - run;
  if (lane == 63) Wsum[wave] = x;
  __syncthreads();
  float boff = 0.f;
  #pragma unroll
  for (int w = 0; w < 4; ++w) if (w < wave) boff += Wsum[w];
  const float cbase = boff + wexcl;

  float a[8], am[8], csum[8];
  float m = -__builtin_inff();
  #pragma unroll
  for (int j = 0; j < 8; ++j) {
    csum[j] = cbase + cs[j];
    a[j] = (it[j] + ib) - csum[j];
    m = fmaxf(m, a[j]);
    am[j] = m;
  }
  float y = m;
  #pragma unroll
  for (int off = 1; off < 64; off <<= 1) {
    const float tv = __shfl_up(y, off, 64);
    if (lane >= off) y = fmaxf(y, tv);
  }
  float e = __shfl_up(y, 1, 64);
  if (lane == 0) e = -__builtin_inff();
  if (lane == 63) Wmax[wave] = y;
  __syncthreads();
  float bmax = -__builtin_inff();
  #pragma unroll
  for (int w = 0; w < 4; ++w) if (w < wave) bmax = fmaxf(bmax, Wmax[w]);
  const float pre = fmaxf(bmax, e);

  float oa[8], ocm[8], oen[8];
  #pragma unroll
  for (int j = 0; j < 8; ++j) {
    const float cm = fmaxf(pre, am[j]);
    oa[j]  = a[j] * LOG2E;
    ocm[j] = cm * LOG2E;
    oen[j] = expf(-(csum[j] + cm));
  }
  *(float4*)&g_aL[base]    = *(float4*)&oa[0];
  *(float4*)&g_aL[base+4]  = *(float4*)&oa[4];
  *(float4*)&g_cmL[base]   = *(float4*)&ocm[0];
  *(float4*)&g_cmL[base+4] = *(float4*)&ocm[4];
  *(float4*)&g_en[base]    = *(float4*)&oen[0];
  *(float4*)&g_en[base+4]  = *(float4*)&oen[4];
}

// ------- kernel 5: fused attention + maxit normalize + GroupNorm -------
// d-SPLIT PV RESTRUCTURE for VGPR <= 128 (the occupancy cliff: rounds 3/7/8
// showed 2 waves/SIMD co-residency happens ONLY at VGPR <= 128; the old
// 32i x 128d per-wave accumulator (64 regs) made that impossible).
// grid = (NH, 64) = 512 blocks of 256 threads -> 2 blocks/CU co-resident.
// bid%8 = head (XCD L2 affinity); heavy-first complement pairing t = y<32 ?
// 63-y : y-32 puts one heavy + one light tile per CU.
// Per visit (128 j): wave w computes QK^T + softmax for j-quarter w (swapped
// 32x32 MFMA, lane = i, cm lane-local; in-register P->bf16 A-frags via
// pack+permlane32_swap), publishes the two 16B frags to double-buffered LDS
// (ONE barrier/visit); then every wave runs PV for its OWN d-quarter over all
// 4 j-quarters: acc = one 32i x 32d tile = 16 VGPRs. Each wave ends with the
// COMPLETE O for its d-slice -> no Osum reduction; epilogue needs only scalar
// cross-wave reductions for rowsum and GroupNorm moments.
__global__ __launch_bounds__(256, 2) void attn_kernel(const float* __restrict__ gnw,
                                                      const float* __restrict__ gnb,
                                                      float* __restrict__ out) {
  __shared__ __align__(16) us8 Ps[2][4][2][64];   // 16 KB: [buf][jq][ph][lane]
  __shared__ float Sq[4][32];
  __shared__ float Sc[32];
  __shared__ float Sn1[4][32];
  __shared__ float Sn2[4][32];
  __shared__ float Mu[32];
  __shared__ float Rstd[32];

  const int h = blockIdx.x;
  const int y = blockIdx.y;            // 0..63
  const int t = (y < 32) ? (63 - y) : (y - 32);   // heavy-first complement pairing
  const int i0 = 32*t;
  const int imax = i0 + 31;
  const int nv = (imax >> 7) + 1;      // 128-col visits (1..16)

  const int tid  = threadIdx.x;
  const int w    = tid >> 6;           // wave 0..3: j-quarter for QK, d-quarter for PV
  const int lane = tid & 63;
  const int l31  = lane & 31;
  const int hi   = lane >> 5;

  const unsigned short* Kgh = g_Kb + (h*SEQ + l31)*HD + hi*8;         // + jw*HD + ks*16
  const unsigned short* Vgh = g_Vt + (h*HD + 32*w + l31)*SEQ + hi*8;  // + j
  const float*          aLh = g_aL + h*SEQ + 4*hi;                    // + jw + 8*rq

  // Q B-fragments (n = i = lane&31)
  bf16x8 qf[8];
  {
    const unsigned short* Qg = g_Qb + (h*SEQ + i0 + l31)*HD + hi*8;
    #pragma unroll
    for (int ks = 0; ks < 8; ++ks) qf[ks] = *(const bf16x8*)&Qg[ks*16];
  }
  const float cm = g_cmL[h*SEQ + i0 + l31];
  const int   ig = i0 + l31;

  f32x16 acc;
  #pragma unroll
  for (int e = 0; e < 16; ++e) acc[e] = 0.f;
  float rs = 0.f;

  for (int jc = 0; jc < nv; ++jc) {
    const int jb  = jc*128;
    const int jw  = jb + 32*w;
    const int buf = jc & 1;

    if (jw <= imax) {
      // QK^T for this wave's 32-j quarter (single MFMA chain; peak regs low)
      bf16x8 kf[8];
      #pragma unroll
      for (int ks = 0; ks < 8; ++ks) kf[ks] = *(const bf16x8*)&Kgh[jw*HD + ks*16];
      f32x16 s;
      #pragma unroll
      for (int e = 0; e < 16; ++e) s[e] = 0.f;
      #pragma unroll
      for (int ks = 0; ks < 8; ++ks)
        s = __builtin_amdgcn_mfma_f32_32x32x16_bf16(kf[ks], qf[ks], s, 0, 0, 0);

      float4 aLq[4];
      #pragma unroll
      for (int rq = 0; rq < 4; ++rq) aLq[rq] = *(const float4*)&aLh[jw + 8*rq];

      const bool needMask = (jw + 31 > i0);   // wave-uniform
      #pragma unroll
      for (int ph = 0; ph < 2; ++ph) {
        float pv[8];
        #pragma unroll
        for (int rr = 0; rr < 8; ++rr) {
          const int r  = 8*ph + rr;
          const int rq = r >> 2;
          const float aL = ((const float*)&aLq[rq])[r & 3];
          float p = s[r] * (exp2f(aL - cm) * INVTAU);
          if (needMask) {
            const int jg = jw + 8*rq + 4*hi + (r & 3);
            if (jg > ig) p = 0.f;
          }
          rs += p;
          pv[rr] = p;
        }
        const unsigned w0 = packbf(pv[0], pv[1]);
        const unsigned w1 = packbf(pv[2], pv[3]);
        const unsigned w2 = packbf(pv[4], pv[5]);
        const unsigned w3 = packbf(pv[6], pv[7]);
        const auto p0 = __builtin_amdgcn_permlane32_swap(w0, w2, false, false);
        const auto p1 = __builtin_amdgcn_permlane32_swap(w1, w3, false, false);
        union { unsigned u[4]; us8 sv; } fr;
        fr.u[0] = p0[0]; fr.u[1] = p1[0]; fr.u[2] = p0[1]; fr.u[3] = p1[1];
        Ps[buf][w][ph][lane] = fr.sv;
      }
    }
    __syncthreads();   // publish Ps[buf]; also guarantees Ps[buf^1] readers done

    // PV over all active j-quarters, this wave's d-quarter (d = 32*w + l31)
    const int nqa = ((imax - jb) >> 5) + 1;
    const int nq  = (nqa < 4) ? nqa : 4;
    for (int jq = 0; jq < nq; ++jq) {
      #pragma unroll
      for (int ph = 0; ph < 2; ++ph) {
        const bf16x8 pf = *(const bf16x8*)&Ps[buf][jq][ph][lane];
        const bf16x8 vb = *(const bf16x8*)&Vgh[jb + jq*32 + 16*ph];
        acc = __builtin_amdgcn_mfma_f32_32x32x16_bf16(pf, vb, acc, 0, 0, 0);
      }
    }
  }

  // ---- epilogue: rowsum reduce, maxit scale, GroupNorm (scalar reductions) ----
  {
    const float rs2 = rs + __shfl_xor(rs, 32, 64);   // combine hi halves (same i)
    if (hi == 0) Sq[w][l31] = rs2;
  }
  __syncthreads();
  if (w == 0 && lane < 32) {
    const float S  = Sq[0][lane] + Sq[1][lane] + Sq[2][lane] + Sq[3][lane];
    const float en = g_en[h*SEQ + i0 + lane];
    Sc[lane] = 1.f / (fmaxf(fabsf(S), en) + 1e-6f);
  }
  __syncthreads();

  // normalize + per-(wave,i) moment partials over this wave's 32 d
  float o[16];
  #pragma unroll
  for (int r = 0; r < 16; ++r) {
    const int irow = (r & 3) + 8*(r >> 2) + 4*hi;   // i index of acc[r]
    const float xv = acc[r] * Sc[irow];
    o[r] = xv;
    float a = xv, b = xv * xv;
    #pragma unroll
    for (int m = 1; m < 32; m <<= 1) { a += __shfl_xor(a, m, 32); b += __shfl_xor(b, m, 32); }
    if (l31 == 0) { Sn1[w][irow] = a; Sn2[w][irow] = b; }
  }
  __syncthreads();
  if (w == 0 && lane < 32) {
    const float s1 = Sn1[0][lane] + Sn1[1][lane] + Sn1[2][lane] + Sn1[3][lane];
    const float s2 = Sn2[0][lane] + Sn2[1][lane] + Sn2[2][lane] + Sn2[3][lane];
    const float mean = s1 * (1.f/128.f);
    const float var  = s2 * (1.f/128.f) - mean*mean;
    Mu[lane]   = mean;
    Rstd[lane] = rsqrtf(var + 1e-5f);
  }
  __syncthreads();

  const float gwv = gnw[h*HD + 32*w + l31];
  const float gbv = gnb[h*HD + 32*w + l31];
  #pragma unroll
  for (int r = 0; r < 16; ++r) {
    const int irow = (r & 3) + 8*(r >> 2) + 4*hi;
    out[(i0 + irow)*DIMF + h*HD + 32*w + l31] =
        (o[r] - Mu[irow]) * Rstd[irow] * gwv + gbv;
  }
}

extern "C" void kernel_launch(void* const* d_in, const int* in_sizes, int n_in,
                              void* d_out, int out_size, void* d_ws, size_t ws_size,
                              hipStream_t stream) {
  (void)in_sizes; (void)n_in; (void)out_size; (void)d_ws; (void)ws_size;
  const float* q    = (const float*)d_in[0];
  const float* k    = (const float*)d_in[1];
  const float* v    = (const float*)d_in[2];
  const float* Wi_w = (const float*)d_in[3];
  const float* Wi_b = (const float*)d_in[4];
  const float* Wf_w = (const float*)d_in[5];
  const float* Wf_b = (const float*)d_in[6];
  const float* gnw  = (const float*)d_in[7];
  const float* gnb  = (const float*)d_in[8];
  float* out = (float*)d_out;

  convert_kernel<<<dim3(6192), 256, 0, stream>>>(q, k, v, Wi_w, Wf_w);
  vtrans_kernel<<<dim3(NH, SEQ/64, HD/64), 256, 0, stream>>>();
  gates_kernel<<<dim3(128), 256, 0, stream>>>();
  scan_kernel<<<dim3(NH), 256, 0, stream>>>(Wi_b, Wf_b);
  attn_kernel<<<dim3(NH, 64), 256, 0, stream>>>(gnw, gnb, out);
}

// Round 11
// 158.310 us; speedup vs baseline: 1.0150x; 1.0150x over previous
//
#include <hip/hip_runtime.h>
#include <math.h>

#define SEQ 2048
#define NH 8
#define HD 128
#define DIMF 1024
#define LOG2E 1.4426950408889634f
#define INVTAU 0.08838834764831845f

typedef __attribute__((ext_vector_type(8))) short bf16x8;
typedef __attribute__((ext_vector_type(8))) unsigned short us8;
typedef __attribute__((ext_vector_type(4))) float f32x4;
typedef __attribute__((ext_vector_type(16))) float f32x16;

// persistent scratch (fully rewritten every launch; no stale-state dependence)
__device__ float g_itacc[NH*SEQ];
__device__ float g_ftacc[NH*SEQ];
__device__ float g_aL[NH*SEQ];     // (itilde - csum) * log2e
__device__ float g_cmL[NH*SEQ];    // cummax(a) * log2e
__device__ float g_en[NH*SEQ];     // exp(-(csum + cummax)) = exp(-max_d)
__device__ unsigned short g_Qb[NH*SEQ*HD];  // bf16, [h][s][d]
__device__ unsigned short g_Kb[NH*SEQ*HD];
__device__ unsigned short g_Vb[NH*SEQ*HD];
__device__ unsigned short g_Vt[NH*HD*SEQ];  // bf16, [h][d][s]  (V transposed)
__device__ unsigned short g_Wb[16*3072];    // bf16, rows 0..7 = Wi, 8..15 = Wf

__device__ __forceinline__ unsigned short f2bf(float x) {
  unsigned u = __float_as_uint(x);
  u += 0x7fffu + ((u >> 16) & 1u);   // RNE
  return (unsigned short)(u >> 16);
}

__device__ __forceinline__ unsigned packbf(float lo, float hi) {
  return (unsigned)f2bf(lo) | ((unsigned)f2bf(hi) << 16);
}

// ------- kernel 1: q/k/v fp32 -> bf16 [h][s][d]  +  Wi/Wf -> bf16 (merged) -------
__global__ __launch_bounds__(256) void convert_kernel(const float* __restrict__ q,
                                                      const float* __restrict__ k,
                                                      const float* __restrict__ v,
                                                      const float* __restrict__ Wi,
                                                      const float* __restrict__ Wf) {
  const int bid = blockIdx.x;
  if (bid < 6144) {
    const int s = bid & 2047;
    const int t = bid >> 11;
    const float* src = (t == 0) ? q : (t == 1) ? k : v;
    unsigned short* dst = (t == 0) ? g_Qb : (t == 1) ? g_Kb : g_Vb;
    const int c = threadIdx.x * 4;
    const float4 f = *(const float4*)(src + s*DIMF + c);
    const int h = c >> 7, d = c & 127;
    ushort4 u;
    u.x = f2bf(f.x); u.y = f2bf(f.y); u.z = f2bf(f.z); u.w = f2bf(f.w);
    *(ushort4*)(dst + (h*SEQ + s)*HD + d) = u;
  } else {
    const int gid = (bid - 6144) * 256 + threadIdx.x;
    const int e4 = gid * 4;           // 48 blocks * 1024 = 49152 = 16*3072 exactly
    const int p = e4 / 3072;
    const int c = e4 % 3072;
    const float* src = (p < 8) ? (Wi + p*3072 + c) : (Wf + (p-8)*3072 + c);
    const float4 f = *(const float4*)src;
    ushort4 u;
    u.x = f2bf(f.x); u.y = f2bf(f.y); u.z = f2bf(f.z); u.w = f2bf(f.w);
    *(ushort4*)(g_Wb + p*3072 + c) = u;
  }
}

// ------- kernel 2: V transpose  g_Vb[h][s][d] -> g_Vt[h][d][s] -------
__global__ __launch_bounds__(256) void vtrans_kernel() {
  __shared__ __align__(16) unsigned short Ts[64*72];
  const int h  = blockIdx.x;
  const int s0 = blockIdx.y * 64;
  const int d0 = blockIdx.z * 64;
  const int t = threadIdx.x;
  { // load 64 s-rows x 64 d-cols, coalesced
    const int sr = t >> 2;
    const int c  = (t & 3) * 16;
    const unsigned short* src = g_Vb + (h*SEQ + s0 + sr)*HD + d0 + c;
    *(us8*)&Ts[sr*72 + c]     = *(const us8*)&src[0];
    *(us8*)&Ts[sr*72 + c + 8] = *(const us8*)&src[8];
  }
  __syncthreads();
  { // store: wave w covers s-cols [w*16,w*16+16), lane l = output d-row
    const int w = t >> 6, l = t & 63;
    unsigned short outv[16];
    #pragma unroll
    for (int j = 0; j < 16; ++j) outv[j] = Ts[(w*16 + j)*72 + l];
    unsigned short* dst = g_Vt + (h*HD + d0 + l)*SEQ + s0 + w*16;
    *(us8*)&dst[0] = *(us8*)&outv[0];
    *(us8*)&dst[8] = *(us8*)&outv[8];
  }
}

// ------- kernel 3: gate projections via MFMA (M=2048, N=16, K=3072) -------
__global__ __launch_bounds__(256) void gates_kernel() {
  __shared__ f32x4 red[4][64];
  const int tid = threadIdx.x;
  const int wave = tid >> 6, lane = tid & 63;
  const int q4 = lane >> 4, l16 = lane & 15;
  const int s0 = blockIdx.x * 16;
  f32x4 acc = {0.f, 0.f, 0.f, 0.f};
  #pragma unroll 8
  for (int ks = wave*24; ks < wave*24 + 24; ++ks) {
    const int k0 = ks*32 + q4*8;          // global k of this lane's 8 elems
    const int tsel = k0 >> 10;
    const int rem = k0 & 1023;
    const int hh = rem >> 7, dd = rem & 127;
    const unsigned short* base = (tsel == 0) ? g_Qb : (tsel == 1) ? g_Kb : g_Vb;
    const bf16x8 a = *(const bf16x8*)&base[(hh*SEQ + s0 + l16)*HD + dd];
    const bf16x8 b = *(const bf16x8*)&g_Wb[l16*3072 + k0];
    acc = __builtin_amdgcn_mfma_f32_16x16x32_bf16(a, b, acc, 0, 0, 0);
  }
  red[wave][lane] = acc;
  __syncthreads();
  if (wave == 0) {
    f32x4 s = red[0][lane];
    #pragma unroll
    for (int w = 1; w < 4; ++w) s += red[w][lane];
    #pragma unroll
    for (int r = 0; r < 4; ++r) {
      const int sg = s0 + 4*q4 + r;       // C/D: row = quad*4+reg, col = l16
      if (l16 < 8) g_itacc[l16*SEQ + sg] = s[r];
      else         g_ftacc[(l16-8)*SEQ + sg] = s[r];
    }
  }
}

// ------- kernel 4: per-head scans (block scan, 256 threads, 8 elems/thread) -------
__global__ __launch_bounds__(256) void scan_kernel(const float* __restrict__ Wi_b,
                                                   const float* __restrict__ Wf_b) {
  __shared__ float Wsum[4];
  __shared__ float Wmax[4];
  const int h = blockIdx.x;
  const int t = threadIdx.x;
  const int wave = t >> 6, lane = t & 63;
  const float ib = Wi_b[h];
  const float fb = Wf_b[h];
  const int base = h*SEQ + t*8;

  float it[8], ft[8];
  *(float4*)&it[0] = *(const float4*)&g_itacc[base];
  *(float4*)&it[4] = *(const float4*)&g_itacc[base+4];
  *(float4*)&ft[0] = *(const float4*)&g_ftacc[base];
  *(float4*)&ft[4] = *(const float4*)&g_ftacc[base+4];

  float cs[8];
  float run = 0.f;
  #pragma unroll
  for (int j = 0; j < 8; ++j) {
    const float f = ft[j] + fb;
    const float ls = fminf(f, 0.f) - log1pf(expf(-fabsf(f)));  // logsigmoid
    run += ls;
    cs[j] = run;
  }
  float x = run;
  #pragma unroll
  for (int off = 1; off < 64; off <<= 1) {
    const float tv = __shfl_up(x, off, 64);
    if (lane >= off) x += tv;
  }
  const float wexcl = x - run;
  if (lane == 63) Wsum[wave] = x;
  __syncthreads();
  float boff = 0.f;
  #pragma unroll
  for (int w = 0; w < 4; ++w) if (w < wave) boff += Wsum[w];
  const float cbase = boff + wexcl;

  float a[8], am[8], csum[8];
  float m = -__builtin_inff();
  #pragma unroll
  for (int j = 0; j < 8; ++j) {
    csum[j] = cbase + cs[j];
    a[j] = (it[j] + ib) - csum[j];
    m = fmaxf(m, a[j]);
    am[j] = m;
  }
  float y = m;
  #pragma unroll
  for (int off = 1; off < 64; off <<= 1) {
    const float tv = __shfl_up(y, off, 64);
    if (lane >= off) y = fmaxf(y, tv);
  }
  float e = __shfl_up(y, 1, 64);
  if (lane == 0) e = -__builtin_inff();
  if (lane == 63) Wmax[wave] = y;
  __syncthreads();
  float bmax = -__builtin_inff();
  #pragma unroll
  for (int w = 0; w < 4; ++w) if (w < wave) bmax = fmaxf(bmax, Wmax[w]);
  const float pre = fmaxf(bmax, e);

  float oa[8], ocm[8], oen[8];
  #pragma unroll
  for (int j = 0; j < 8; ++j) {
    const float cm = fmaxf(pre, am[j]);
    oa[j]  = a[j] * LOG2E;
    ocm[j] = cm * LOG2E;
    oen[j] = expf(-(csum[j] + cm));
  }
  *(float4*)&g_aL[base]    = *(float4*)&oa[0];
  *(float4*)&g_aL[base+4]  = *(float4*)&oa[4];
  *(float4*)&g_cmL[base]   = *(float4*)&ocm[0];
  *(float4*)&g_cmL[base+4] = *(float4*)&ocm[4];
  *(float4*)&g_en[base]    = *(float4*)&oen[0];
  *(float4*)&g_en[base+4]  = *(float4*)&oen[4];
}

// ------- kernel 5: fused attention + maxit normalize + GroupNorm -------
// d-split structure (round 10, passed) with the visit's memory schedule fixed:
// (a) ALL 8 V fragments batched into registers at visit START -- consumed last
//     (PV), so the L2 latency hides under QK+softmax and the __syncthreads
//     vmcnt drain is free; (b) inactive Ps quarters ZERO-FILLED so PV is an
//     unconditional fully-unrolled 4x2 loop with zero loads inside (round 10's
//     runtime-bounded jq loop serialized ~4 L2 round-trips per visit -- the
//     9k-cycle visit); (c) all 8 K loads batched (one exposed latency/visit).
// (256,2) caps VGPR at 128: round 10's 64-VGPR allocation was the compiler
// STARVING the schedule; the headroom is spent on load batching.
// grid = (NH, 64) = 512 blocks -> 2 blocks/CU co-resident (18 KB LDS).
// bid%8 = head (XCD L2 affinity); complement pairing t = y<32 ? 63-y : y-32.
__global__ __launch_bounds__(256, 2) void attn_kernel(const float* __restrict__ gnw,
                                                      const float* __restrict__ gnb,
                                                      float* __restrict__ out) {
  __shared__ __align__(16) us8 Ps[2][4][2][64];   // 16 KB: [buf][jq][ph][lane]
  __shared__ float Sq[4][32];
  __shared__ float Sc[32];
  __shared__ float Sn1[4][32];
  __shared__ float Sn2[4][32];
  __shared__ float Mu[32];
  __shared__ float Rstd[32];

  const int h = blockIdx.x;
  const int y = blockIdx.y;            // 0..63
  const int t = (y < 32) ? (63 - y) : (y - 32);   // heavy-first complement pairing
  const int i0 = 32*t;
  const int imax = i0 + 31;
  const int nv = (imax >> 7) + 1;      // 128-col visits (1..16)

  const int tid  = threadIdx.x;
  const int w    = tid >> 6;           // wave 0..3: j-quarter for QK, d-quarter for PV
  const int lane = tid & 63;
  const int l31  = lane & 31;
  const int hi   = lane >> 5;

  const unsigned short* Kgh = g_Kb + (h*SEQ + l31)*HD + hi*8;         // + jw*HD + ks*16
  const unsigned short* Vgh = g_Vt + (h*HD + 32*w + l31)*SEQ + hi*8;  // + j
  const float*          aLh = g_aL + h*SEQ + 4*hi;                    // + jw + 8*rq

  // Q B-fragments (n = i = lane&31)
  bf16x8 qf[8];
  {
    const unsigned short* Qg = g_Qb + (h*SEQ + i0 + l31)*HD + hi*8;
    #pragma unroll
    for (int ks = 0; ks < 8; ++ks) qf[ks] = *(const bf16x8*)&Qg[ks*16];
  }
  const float cm = g_cmL[h*SEQ + i0 + l31];
  const int   ig = i0 + l31;

  f32x16 acc;
  #pragma unroll
  for (int e = 0; e < 16; ++e) acc[e] = 0.f;
  float rs = 0.f;

  for (int jc = 0; jc < nv; ++jc) {
    const int jb  = jc*128;
    const int jw  = jb + 32*w;
    const int buf = jc & 1;

    // (a) batch ALL V fragments for this visit first: consumed in PV (last),
    // so this latency is covered by the QK+softmax work below.
    bf16x8 vb[8];
    #pragma unroll
    for (int q = 0; q < 4; ++q)
      #pragma unroll
      for (int ph = 0; ph < 2; ++ph)
        vb[q*2 + ph] = *(const bf16x8*)&Vgh[jb + q*32 + 16*ph];

    if (jw <= imax) {
      // (c) batch all 8 K fragments (single exposed L2 latency)
      bf16x8 kf[8];
      #pragma unroll
      for (int ks = 0; ks < 8; ++ks) kf[ks] = *(const bf16x8*)&Kgh[jw*HD + ks*16];
      float4 aLq[4];
      #pragma unroll
      for (int rq = 0; rq < 4; ++rq) aLq[rq] = *(const float4*)&aLh[jw + 8*rq];

      f32x16 s;
      #pragma unroll
      for (int e = 0; e < 16; ++e) s[e] = 0.f;
      #pragma unroll
      for (int ks = 0; ks < 8; ++ks)
        s = __builtin_amdgcn_mfma_f32_32x32x16_bf16(kf[ks], qf[ks], s, 0, 0, 0);

      const bool needMask = (jw + 31 > i0);   // wave-uniform
      #pragma unroll
      for (int ph = 0; ph < 2; ++ph) {
        float pv[8];
        #pragma unroll
        for (int rr = 0; rr < 8; ++rr) {
          const int r  = 8*ph + rr;
          const int rq = r >> 2;
          const float aL = ((const float*)&aLq[rq])[r & 3];
          float p = s[r] * (exp2f(aL - cm) * INVTAU);
          if (needMask) {
            const int jg = jw + 8*rq + 4*hi + (r & 3);
            if (jg > ig) p = 0.f;
          }
          rs += p;
          pv[rr] = p;
        }
        const unsigned w0 = packbf(pv[0], pv[1]);
        const unsigned w1 = packbf(pv[2], pv[3]);
        const unsigned w2 = packbf(pv[4], pv[5]);
        const unsigned w3 = packbf(pv[6], pv[7]);
        const auto p0 = __builtin_amdgcn_permlane32_swap(w0, w2, false, false);
        const auto p1 = __builtin_amdgcn_permlane32_swap(w1, w3, false, false);
        union { unsigned u[4]; us8 sv; } fr;
        fr.u[0] = p0[0]; fr.u[1] = p1[0]; fr.u[2] = p0[1]; fr.u[3] = p1[1];
        Ps[buf][w][ph][lane] = fr.sv;
      }
    } else {
      // (b) zero-fill my inactive quarter so PV can run unconditionally
      const us8 z = {0, 0, 0, 0, 0, 0, 0, 0};
      Ps[buf][w][0][lane] = z;
      Ps[buf][w][1][lane] = z;
    }
    __syncthreads();   // publish Ps[buf]; vb already ~a full QK-phase old

    // (b) PV: unconditional, fully unrolled, zero loads inside
    #pragma unroll
    for (int q = 0; q < 4; ++q)
      #pragma unroll
      for (int ph = 0; ph < 2; ++ph) {
        const bf16x8 pf = *(const bf16x8*)&Ps[buf][q][ph][lane];
        acc = __builtin_amdgcn_mfma_f32_32x32x16_bf16(pf, vb[q*2 + ph], acc, 0, 0, 0);
      }
  }

  // ---- epilogue: rowsum reduce, maxit scale, GroupNorm (scalar reductions) ----
  {
    const float rs2 = rs + __shfl_xor(rs, 32, 64);   // combine hi halves (same i)
    if (hi == 0) Sq[w][l31] = rs2;
  }
  __syncthreads();
  if (w == 0 && lane < 32) {
    const float S  = Sq[0][lane] + Sq[1][lane] + Sq[2][lane] + Sq[3][lane];
    const float en = g_en[h*SEQ + i0 + lane];
    Sc[lane] = 1.f / (fmaxf(fabsf(S), en) + 1e-6f);
  }
  __syncthreads();

  // normalize + per-(wave,i) moment partials over this wave's 32 d
  float o[16];
  #pragma unroll
  for (int r = 0; r < 16; ++r) {
    const int irow = (r & 3) + 8*(r >> 2) + 4*hi;   // i index of acc[r]
    const float xv = acc[r] * Sc[irow];
    o[r] = xv;
    float a = xv, b = xv * xv;
    #pragma unroll
    for (int m = 1; m < 32; m <<= 1) { a += __shfl_xor(a, m, 32); b += __shfl_xor(b, m, 32); }
    if (l31 == 0) { Sn1[w][irow] = a; Sn2[w][irow] = b; }
  }
  __syncthreads();
  if (w == 0 && lane < 32) {
    const float s1 = Sn1[0][lane] + Sn1[1][lane] + Sn1[2][lane] + Sn1[3][lane];
    const float s2 = Sn2[0][lane] + Sn2[1][lane] + Sn2[2][lane] + Sn2[3][lane];
    const float mean = s1 * (1.f/128.f);
    const float var  = s2 * (1.f/128.f) - mean*mean;
    Mu[lane]   = mean;
    Rstd[lane] = rsqrtf(var + 1e-5f);
  }
  __syncthreads();

  const float gwv = gnw[h*HD + 32*w + l31];
  const float gbv = gnb[h*HD + 32*w + l31];
  #pragma unroll
  for (int r = 0; r < 16; ++r) {
    const int irow = (r & 3) + 8*(r >> 2) + 4*hi;
    out[(i0 + irow)*DIMF + h*HD + 32*w + l31] =
        (o[r] - Mu[irow]) * Rstd[irow] * gwv + gbv;
  }
}

extern "C" void kernel_launch(void* const* d_in, const int* in_sizes, int n_in,
                              void* d_out, int out_size, void* d_ws, size_t ws_size,
                              hipStream_t stream) {
  (void)in_sizes; (void)n_in; (void)out_size; (void)d_ws; (void)ws_size;
  const float* q    = (const float*)d_in[0];
  const float* k    = (const float*)d_in[1];
  const float* v    = (const float*)d_in[2];
  const float* Wi_w = (const float*)d_in[3];
  const float* Wi_b = (const float*)d_in[4];
  const float* Wf_w = (const float*)d_in[5];
  const float* Wf_b = (const float*)d_in[6];
  const float* gnw  = (const float*)d_in[7];
  const float* gnb  = (const float*)d_in[8];
  float* out = (float*)d_out;

  convert_kernel<<<dim3(6192), 256, 0, stream>>>(q, k, v, Wi_w, Wf_w);
  vtrans_kernel<<<dim3(NH, SEQ/64, HD/64), 256, 0, stream>>>();
  gates_kernel<<<dim3(128), 256, 0, stream>>>();
  scan_kernel<<<dim3(NH), 256, 0, stream>>>(Wi_b, Wf_b);
  attn_kernel<<<dim3(NH, 64), 256, 0, stream>>>(gnw, gnb, out);
}